// Round 3
// baseline (145.314 us; speedup 1.0000x reference)
//
#include <hip/hip_runtime.h>
#include <hip/hip_bf16.h>

#define S_TOT 50000
#define S_PAD 50048      // 782 * 64
#define NTILES 782
#define HD 128
// (1/sqrt(128)) * log2(e) — folded into queries so exp(x) == exp2(score)
#define QSCALE 0.12751743342f

typedef float f32x4 __attribute__((ext_vector_type(4)));
typedef short s16x8 __attribute__((ext_vector_type(8)));

__device__ __forceinline__ f32x4 mfma_bf16(s16x8 a, s16x8 b, f32x4 c) {
  return __builtin_amdgcn_mfma_f32_16x16x32_bf16(a, b, c, 0, 0, 0);
}

__device__ __forceinline__ short f2bf(float x) {
  __hip_bfloat16 h = __float2bfloat16(x);
  return *reinterpret_cast<short*>(&h);
}

__device__ __forceinline__ s16x8 pack8v(f32x4 a, f32x4 b) {
  s16x8 v;
  v[0] = f2bf(a[0]); v[1] = f2bf(a[1]); v[2] = f2bf(a[2]); v[3] = f2bf(a[3]);
  v[4] = f2bf(b[0]); v[5] = f2bf(b[1]); v[6] = f2bf(b[2]); v[7] = f2bf(b[3]);
  return v;
}

// async 16B global->LDS; lds ptr must be wave-uniform (HW adds lane*16)
__device__ __forceinline__ void gload16(const void* g, void* l) {
  __builtin_amdgcn_global_load_lds(
      (const __attribute__((address_space(1))) unsigned int*)g,
      (__attribute__((address_space(3))) unsigned int*)l, 16, 0, 0);
}

// Stage 64 key rows (16 KB) into buf with XOR-swizzle applied via the GLOBAL
// address (LDS dest stays linear per global_load_lds's base+lane*16 rule).
#define STAGE(buf, tt)                                                      \
  do {                                                                      \
    const char* srcb_ = (const char*)(keys + (size_t)(tt) * 64 * HD);       \
    _Pragma("unroll") for (int u_ = 0; u_ < 4; ++u_) {                      \
      int row_ = u_ * 16 + (tid >> 4);                                      \
      const char* gp_ = srcb_ + row_ * 256 + (((tid & 15) ^ (row_ & 7)) * 16); \
      gload16(gp_, (unsigned char*)(buf) + u_ * 4096 + wid * 1024);         \
    }                                                                       \
  } while (0)

// dst[row,:] = (emb[sel(row)] @ W^T + bias) * scalef  as bf16; rows >= valid -> 0.
// W (128x128 f32, L2-resident) held entirely in registers as 32 b-frags.
// Also zeroes zbuf[0..zn) (runs before pass1 in stream order).
__global__ __launch_bounds__(256) void prep_mfma(
    const float* __restrict__ emb, const float* __restrict__ W,
    const float* __restrict__ bias, const int* __restrict__ idcs,
    __hip_bfloat16* __restrict__ dst, int ntiles, int valid_rows, float scalef,
    float* __restrict__ zbuf, int zn)
{
  const int tid = threadIdx.x;
  const int wid = tid >> 6;
  const int lane = tid & 63;
  const int r16 = lane & 15;
  const int g = lane >> 4;

  if (zbuf) {
    for (int i = blockIdx.x * 256 + tid; i < zn; i += (int)gridDim.x * 256)
      zbuf[i] = 0.f;
  }

  s16x8 bfr[8][4];
#pragma unroll
  for (int jg = 0; jg < 8; ++jg) {
    const float* wp = W + (size_t)(jg * 16 + r16) * HD;
#pragma unroll
    for (int c = 0; c < 4; ++c) {
      f32x4 w0 = *(const f32x4*)(wp + c * 32 + g * 8);
      f32x4 w1 = *(const f32x4*)(wp + c * 32 + g * 8 + 4);
      bfr[jg][c] = pack8v(w0, w1);
    }
  }
  float bsc[8];
#pragma unroll
  for (int jg = 0; jg < 8; ++jg) bsc[jg] = bias[jg * 16 + r16] * scalef;

  for (int tt = blockIdx.x * 4 + wid; tt < ntiles; tt += (int)gridDim.x * 4) {
    int row = tt * 16 + r16;
    int er = (row < valid_rows) ? (idcs ? idcs[row] : row) : (valid_rows - 1);
    const float* ep = emb + (size_t)er * HD;
    s16x8 af[4];
#pragma unroll
    for (int c = 0; c < 4; ++c) {
      f32x4 e0 = *(const f32x4*)(ep + c * 32 + g * 8);
      f32x4 e1 = *(const f32x4*)(ep + c * 32 + g * 8 + 4);
      af[c] = pack8v(e0, e1);
    }
#pragma unroll
    for (int jg = 0; jg < 8; ++jg) {
      f32x4 acc = {0.f, 0.f, 0.f, 0.f};
#pragma unroll
      for (int c = 0; c < 4; ++c) acc = mfma_bf16(af[c], bfr[jg][c], acc);
#pragma unroll
      for (int r = 0; r < 4; ++r) {
        int ro = tt * 16 + 4 * g + r;
        float val = (ro < valid_rows) ? acc[r] * scalef + bsc[jg] : 0.f;
        dst[(size_t)ro * HD + jg * 16 + r16] = __float2bfloat16(val);
      }
    }
  }
}

// pass1: l[row] = sum_s exp2(q[row] . keys[s])   (scale*log2e pre-folded in q)
// 64 q-rows/wave, double-buffered global_load_lds staging, 1 barrier/tile.
__global__ __launch_bounds__(256) void pass1(
    const __hip_bfloat16* __restrict__ keys,
    const __hip_bfloat16* __restrict__ qrs,
    float* __restrict__ lsum)
{
  __shared__ __align__(16) unsigned char kt[2][16384];
  const int tid = threadIdx.x;
  const int wid = tid >> 6;
  const int lane = tid & 63;
  const int r16 = lane & 15;
  const int g = lane >> 4;
  const int rowbase = blockIdx.x * 256 + wid * 64;
  const int gy = gridDim.y;

  s16x8 af[4][4];
#pragma unroll
  for (int rt = 0; rt < 4; ++rt) {
    const unsigned short* qp =
        (const unsigned short*)qrs + (size_t)(rowbase + rt * 16 + r16) * HD;
#pragma unroll
    for (int c = 0; c < 4; ++c)
      af[rt][c] = *(const s16x8*)(qp + c * 32 + g * 8);
  }
  float sums[4][4] = {};
  int cur = 0;
  STAGE(kt[0], blockIdx.y);
  for (int t = blockIdx.y; t < NTILES; t += gy) {
    __syncthreads();  // staged kt[cur] ready (vmcnt drained at barrier)
    int tn = t + gy;
    if (tn < NTILES) STAGE(kt[cur ^ 1], tn);
    const unsigned char* ktc = kt[cur];
    const int s0 = t * 64;
#pragma unroll
    for (int j = 0; j < 4; ++j) {
      f32x4 a[4];
#pragma unroll
      for (int rt = 0; rt < 4; ++rt) a[rt] = f32x4{0.f, 0.f, 0.f, 0.f};
      const int srow = j * 16 + r16;
      const unsigned char* kr = ktc + srow * 256;
      const int sw = (srow & 7) << 4;
#pragma unroll
      for (int c = 0; c < 4; ++c) {
        s16x8 bf = *(const s16x8*)(kr + ((c * 64 + g * 16) ^ sw));
#pragma unroll
        for (int rt = 0; rt < 4; ++rt) a[rt] = mfma_bf16(af[rt][c], bf, a[rt]);
      }
      if (s0 + j * 16 + r16 < S_TOT) {
#pragma unroll
        for (int rt = 0; rt < 4; ++rt)
#pragma unroll
          for (int r = 0; r < 4; ++r) sums[rt][r] += exp2f(a[rt][r]);
      }
    }
    cur ^= 1;
  }
#pragma unroll
  for (int rt = 0; rt < 4; ++rt) {
#pragma unroll
    for (int r = 0; r < 4; ++r) {
      float v = sums[rt][r];
      v += __shfl_xor(v, 1, 64);
      v += __shfl_xor(v, 2, 64);
      v += __shfl_xor(v, 4, 64);
      v += __shfl_xor(v, 8, 64);
      if (r16 == 0) atomicAdd(&lsum[rowbase + rt * 16 + g * 4 + r], v);
    }
  }
}

// pass2: out[b,s] = sum_k (belief[b,k]/l[b,k]) * exp2(score)
// 2 batches per block; each wave owns 64 k-rows of one batch.
__global__ __launch_bounds__(256) void pass2(
    const __hip_bfloat16* __restrict__ keys,
    const __hip_bfloat16* __restrict__ qrs,
    const float* __restrict__ lsum,
    const float* __restrict__ belief,
    float* __restrict__ out)
{
  __shared__ __align__(16) unsigned char kt[2][16384];
  __shared__ float outs[2][64];
  const int tid = threadIdx.x;
  const int wid = tid >> 6;
  const int lane = tid & 63;
  const int r16 = lane & 15;
  const int g = lane >> 4;
  const int rowbase = blockIdx.x * 256 + wid * 64;
  const int bloc = wid >> 1;
  const int gy = gridDim.y;

  s16x8 af[4][4];
  float wq[4][4];
#pragma unroll
  for (int rt = 0; rt < 4; ++rt) {
    const unsigned short* qp =
        (const unsigned short*)qrs + (size_t)(rowbase + rt * 16 + r16) * HD;
#pragma unroll
    for (int c = 0; c < 4; ++c)
      af[rt][c] = *(const s16x8*)(qp + c * 32 + g * 8);
#pragma unroll
    for (int r = 0; r < 4; ++r) {
      int row = rowbase + rt * 16 + 4 * g + r;
      wq[rt][r] = belief[row] / lsum[row];
    }
  }
  int cur = 0;
  STAGE(kt[0], blockIdx.y);
  if (tid < 128) outs[tid >> 6][tid & 63] = 0.f;
  for (int t = blockIdx.y; t < NTILES; t += gy) {
    __syncthreads();  // staged kt[cur] ready; outs zeroed
    int tn = t + gy;
    if (tn < NTILES) STAGE(kt[cur ^ 1], tn);
    const unsigned char* ktc = kt[cur];
#pragma unroll
    for (int j = 0; j < 4; ++j) {
      f32x4 a[4];
#pragma unroll
      for (int rt = 0; rt < 4; ++rt) a[rt] = f32x4{0.f, 0.f, 0.f, 0.f};
      const int srow = j * 16 + r16;
      const unsigned char* kr = ktc + srow * 256;
      const int sw = (srow & 7) << 4;
#pragma unroll
      for (int c = 0; c < 4; ++c) {
        s16x8 bf = *(const s16x8*)(kr + ((c * 64 + g * 16) ^ sw));
#pragma unroll
        for (int rt = 0; rt < 4; ++rt) a[rt] = mfma_bf16(af[rt][c], bf, a[rt]);
      }
      float v = 0.f;
#pragma unroll
      for (int rt = 0; rt < 4; ++rt)
#pragma unroll
        for (int r = 0; r < 4; ++r) v += wq[rt][r] * exp2f(a[rt][r]);
      v += __shfl_xor(v, 16, 64);
      v += __shfl_xor(v, 32, 64);
      if (g == 0) atomicAdd(&outs[bloc][j * 16 + r16], v);
    }
    __syncthreads();  // outs complete
    if (tid < 128) {
      int s = t * 64 + (tid & 63);
      if (s < S_TOT)
        out[(size_t)(blockIdx.x * 2 + (tid >> 6)) * S_TOT + s] =
            outs[tid >> 6][tid & 63];
      outs[tid >> 6][tid & 63] = 0.f;  // next iteration's barrier protects
    }
    cur ^= 1;
  }
}

extern "C" void kernel_launch(void* const* d_in, const int* in_sizes, int n_in,
                              void* d_out, int out_size, void* d_ws, size_t ws_size,
                              hipStream_t stream) {
  const float* state_emb = (const float*)d_in[0];
  const float* Wk = (const float*)d_in[1];
  const float* bk = (const float*)d_in[2];
  const float* Wq = (const float*)d_in[3];
  const float* bq = (const float*)d_in[4];
  const float* belief = (const float*)d_in[5];
  const int* idcs = (const int*)d_in[6];
  float* out = (float*)d_out;

  __hip_bfloat16* keys = (__hip_bfloat16*)d_ws;                 // S_PAD*128 bf16
  __hip_bfloat16* qrs = keys + (size_t)S_PAD * HD;              // 2048*128 bf16
  float* lsum = (float*)(qrs + (size_t)2048 * HD);              // 2048 f32

  prep_mfma<<<782, 256, 0, stream>>>(state_emb, Wk, bk, nullptr, keys,
                                     S_PAD / 16, S_TOT, 1.0f, lsum, 2048);
  prep_mfma<<<32, 256, 0, stream>>>(state_emb, Wq, bq, idcs, qrs,
                                    128, 2048, QSCALE, nullptr, 0);
  pass1<<<dim3(8, 128), 256, 0, stream>>>(keys, qrs, lsum);
  pass2<<<dim3(8, 128), 256, 0, stream>>>(keys, qrs, lsum, belief, out);
}

// Round 4
// 122.343 us; speedup vs baseline: 1.1878x; 1.1878x over previous
//
#include <hip/hip_runtime.h>
#include <hip/hip_bf16.h>

#define S_TOT 50000
#define S_PAD 50048      // 782 * 64
#define NTILES 782
#define HD 128
// (1/sqrt(128)) * log2(e) — folded into queries so exp(score)==exp2(q.k)
#define QSCALE 0.1275174036f

typedef float f32x4 __attribute__((ext_vector_type(4)));
typedef short s16x8 __attribute__((ext_vector_type(8)));

__device__ __forceinline__ f32x4 mfma_bf16(s16x8 a, s16x8 b, f32x4 c) {
  return __builtin_amdgcn_mfma_f32_16x16x32_bf16(a, b, c, 0, 0, 0);
}

__device__ __forceinline__ float fexp2(float x) {
#if __has_builtin(__builtin_amdgcn_exp2f)
  return __builtin_amdgcn_exp2f(x);
#else
  float r;
  asm("v_exp_f32 %0, %1" : "=v"(r) : "v"(x));
  return r;
#endif
}

__device__ __forceinline__ short f2bf(float x) {
  __hip_bfloat16 h = __float2bfloat16(x);
  return *reinterpret_cast<short*>(&h);
}

__device__ __forceinline__ s16x8 pack8v(f32x4 a, f32x4 b) {
  s16x8 v;
  v[0] = f2bf(a[0]); v[1] = f2bf(a[1]); v[2] = f2bf(a[2]); v[3] = f2bf(a[3]);
  v[4] = f2bf(b[0]); v[5] = f2bf(b[1]); v[6] = f2bf(b[2]); v[7] = f2bf(b[3]);
  return v;
}

// async 16B global->LDS; lds ptr must be wave-uniform (HW adds lane*16)
__device__ __forceinline__ void gload16(const void* g, void* l) {
  __builtin_amdgcn_global_load_lds(
      (const __attribute__((address_space(1))) unsigned int*)g,
      (__attribute__((address_space(3))) unsigned int*)l, 16, 0, 0);
}

// Stage 64 key rows (16 KB) into buf; XOR-swizzle applied via the GLOBAL
// address (LDS dest stays linear per global_load_lds's base+lane*16 rule).
#define STAGE(buf, tt)                                                      \
  do {                                                                      \
    const char* srcb_ = (const char*)(keys + (size_t)(tt) * 64 * HD);       \
    _Pragma("unroll") for (int u_ = 0; u_ < 4; ++u_) {                      \
      int row_ = u_ * 16 + (tid >> 4);                                      \
      const char* gp_ = srcb_ + row_ * 256 + (((tid & 15) ^ (row_ & 7)) * 16); \
      gload16(gp_, (unsigned char*)(buf) + u_ * 4096 + wid * 1024);         \
    }                                                                       \
  } while (0)

// dst[row,:] = (emb[sel(row)] @ W^T + bias) * scalef  as bf16; rows>=valid -> 0.
// W (128x128 f32, L2-resident) held entirely in registers as 32 b-frags.
// Also zeroes zbuf[0..zn) (runs before pass1 in stream order).
__global__ __launch_bounds__(256) void prep_mfma(
    const float* __restrict__ emb, const float* __restrict__ W,
    const float* __restrict__ bias, const int* __restrict__ idcs,
    __hip_bfloat16* __restrict__ dst, int ntiles, int valid_rows, float scalef,
    float* __restrict__ zbuf, int zn)
{
  const int tid = threadIdx.x;
  const int wid = tid >> 6;
  const int lane = tid & 63;
  const int r16 = lane & 15;
  const int g = lane >> 4;

  if (zbuf) {
    for (int i = blockIdx.x * 256 + tid; i < zn; i += (int)gridDim.x * 256)
      zbuf[i] = 0.f;
  }

  s16x8 bfr[8][4];
#pragma unroll
  for (int jg = 0; jg < 8; ++jg) {
    const float* wp = W + (size_t)(jg * 16 + r16) * HD;
#pragma unroll
    for (int c = 0; c < 4; ++c) {
      f32x4 w0 = *(const f32x4*)(wp + c * 32 + g * 8);
      f32x4 w1 = *(const f32x4*)(wp + c * 32 + g * 8 + 4);
      bfr[jg][c] = pack8v(w0, w1);
    }
  }
  float bsc[8];
#pragma unroll
  for (int jg = 0; jg < 8; ++jg) bsc[jg] = bias[jg * 16 + r16] * scalef;

  for (int tt = blockIdx.x * 4 + wid; tt < ntiles; tt += (int)gridDim.x * 4) {
    int row = tt * 16 + r16;
    int er = (row < valid_rows) ? (idcs ? idcs[row] : row) : (valid_rows - 1);
    const float* ep = emb + (size_t)er * HD;
    s16x8 af[4];
#pragma unroll
    for (int c = 0; c < 4; ++c) {
      f32x4 e0 = *(const f32x4*)(ep + c * 32 + g * 8);
      f32x4 e1 = *(const f32x4*)(ep + c * 32 + g * 8 + 4);
      af[c] = pack8v(e0, e1);
    }
#pragma unroll
    for (int jg = 0; jg < 8; ++jg) {
      f32x4 acc = {0.f, 0.f, 0.f, 0.f};
#pragma unroll
      for (int c = 0; c < 4; ++c) acc = mfma_bf16(af[c], bfr[jg][c], acc);
#pragma unroll
      for (int r = 0; r < 4; ++r) {
        int ro = tt * 16 + 4 * g + r;
        float val = (ro < valid_rows) ? acc[r] * scalef + bsc[jg] : 0.f;
        dst[(size_t)ro * HD + jg * 16 + r16] = __float2bfloat16(val);
      }
    }
  }
}

// pass1: l[row] = sum_s exp2(q[row].keys[s]).  128 q-rows/wave, 8:1 MFMA:ds_read,
// double-buffered global_load_lds staging, 1 barrier/tile.
__global__ __launch_bounds__(256) void pass1(
    const __hip_bfloat16* __restrict__ keys,
    const __hip_bfloat16* __restrict__ qrs,
    float* __restrict__ lsum)
{
  __shared__ __align__(16) unsigned char kt[2][16384];
  const int tid = threadIdx.x;
  const int wid = tid >> 6;
  const int lane = tid & 63;
  const int r16 = lane & 15;
  const int g = lane >> 4;
  const int rowbase = blockIdx.x * 512 + wid * 128;
  const int gy = gridDim.y;

  s16x8 af[8][4];
#pragma unroll
  for (int rt = 0; rt < 8; ++rt) {
    const unsigned short* qp =
        (const unsigned short*)qrs + (size_t)(rowbase + rt * 16 + r16) * HD;
#pragma unroll
    for (int c = 0; c < 4; ++c)
      af[rt][c] = *(const s16x8*)(qp + c * 32 + g * 8);
  }
  float sums[8][4] = {};
  int cur = 0;
  STAGE(kt[0], blockIdx.y);
  for (int t = blockIdx.y; t < NTILES; t += gy) {
    __syncthreads();  // staged kt[cur] ready (vmcnt drained at barrier)
    int tn = t + gy;
    if (tn < NTILES) STAGE(kt[cur ^ 1], tn);
    const unsigned char* ktc = kt[cur];
    const int s0 = t * 64;
#pragma unroll
    for (int j = 0; j < 4; ++j) {
      f32x4 a[8];
#pragma unroll
      for (int rt = 0; rt < 8; ++rt) a[rt] = f32x4{0.f, 0.f, 0.f, 0.f};
      const int srow = j * 16 + r16;
      const unsigned char* kr = ktc + srow * 256;
      const int sw = (srow & 7) << 4;
#pragma unroll
      for (int c = 0; c < 4; ++c) {
        s16x8 bf = *(const s16x8*)(kr + ((c * 64 + g * 16) ^ sw));
#pragma unroll
        for (int rt = 0; rt < 8; ++rt) a[rt] = mfma_bf16(af[rt][c], bf, a[rt]);
      }
      if (s0 + j * 16 + r16 < S_TOT) {
#pragma unroll
        for (int rt = 0; rt < 8; ++rt)
#pragma unroll
          for (int r = 0; r < 4; ++r) sums[rt][r] += fexp2(a[rt][r]);
      }
    }
    cur ^= 1;
  }
#pragma unroll
  for (int rt = 0; rt < 8; ++rt) {
#pragma unroll
    for (int r = 0; r < 4; ++r) {
      float v = sums[rt][r];
      v += __shfl_xor(v, 1, 64);
      v += __shfl_xor(v, 2, 64);
      v += __shfl_xor(v, 4, 64);
      v += __shfl_xor(v, 8, 64);
      if (r16 == 0) atomicAdd(&lsum[rowbase + rt * 16 + g * 4 + r], v);
    }
  }
}

// pass2: out[b,s] = sum_k (belief[b,k]/l[b,k]) * exp2(score).
// One full batch (128 k-rows) per wave -> register accumulation, direct
// stores, no LDS outs / atomics / second barrier.
__global__ __launch_bounds__(256) void pass2(
    const __hip_bfloat16* __restrict__ keys,
    const __hip_bfloat16* __restrict__ qrs,
    const float* __restrict__ lsum,
    const float* __restrict__ belief,
    float* __restrict__ out)
{
  __shared__ __align__(16) unsigned char kt[2][16384];
  const int tid = threadIdx.x;
  const int wid = tid >> 6;
  const int lane = tid & 63;
  const int r16 = lane & 15;
  const int g = lane >> 4;
  const int rowbase = blockIdx.x * 512 + wid * 128;
  const int b = blockIdx.x * 4 + wid;
  const int gy = gridDim.y;

  s16x8 af[8][4];
  float wq[8][4];
#pragma unroll
  for (int rt = 0; rt < 8; ++rt) {
    const unsigned short* qp =
        (const unsigned short*)qrs + (size_t)(rowbase + rt * 16 + r16) * HD;
#pragma unroll
    for (int c = 0; c < 4; ++c)
      af[rt][c] = *(const s16x8*)(qp + c * 32 + g * 8);
#pragma unroll
    for (int r = 0; r < 4; ++r) {
      int row = rowbase + rt * 16 + 4 * g + r;
      wq[rt][r] = belief[row] / lsum[row];
    }
  }
  int cur = 0;
  STAGE(kt[0], blockIdx.y);
  for (int t = blockIdx.y; t < NTILES; t += gy) {
    __syncthreads();  // staged kt[cur] ready
    int tn = t + gy;
    if (tn < NTILES) STAGE(kt[cur ^ 1], tn);
    const unsigned char* ktc = kt[cur];
    const int s0 = t * 64;
#pragma unroll
    for (int j = 0; j < 4; ++j) {
      f32x4 a[8];
#pragma unroll
      for (int rt = 0; rt < 8; ++rt) a[rt] = f32x4{0.f, 0.f, 0.f, 0.f};
      const int srow = j * 16 + r16;
      const unsigned char* kr = ktc + srow * 256;
      const int sw = (srow & 7) << 4;
#pragma unroll
      for (int c = 0; c < 4; ++c) {
        s16x8 bf = *(const s16x8*)(kr + ((c * 64 + g * 16) ^ sw));
#pragma unroll
        for (int rt = 0; rt < 8; ++rt) a[rt] = mfma_bf16(af[rt][c], bf, a[rt]);
      }
      float v = 0.f;
#pragma unroll
      for (int rt = 0; rt < 8; ++rt)
#pragma unroll
        for (int r = 0; r < 4; ++r) v = fmaf(wq[rt][r], fexp2(a[rt][r]), v);
      v += __shfl_xor(v, 16, 64);
      v += __shfl_xor(v, 32, 64);
      int s = s0 + j * 16 + r16;
      if (g == 0 && s < S_TOT) out[(size_t)b * S_TOT + s] = v;
    }
    cur ^= 1;
  }
}

extern "C" void kernel_launch(void* const* d_in, const int* in_sizes, int n_in,
                              void* d_out, int out_size, void* d_ws, size_t ws_size,
                              hipStream_t stream) {
  const float* state_emb = (const float*)d_in[0];
  const float* Wk = (const float*)d_in[1];
  const float* bk = (const float*)d_in[2];
  const float* Wq = (const float*)d_in[3];
  const float* bq = (const float*)d_in[4];
  const float* belief = (const float*)d_in[5];
  const int* idcs = (const int*)d_in[6];
  float* out = (float*)d_out;

  __hip_bfloat16* keys = (__hip_bfloat16*)d_ws;                 // S_PAD*128 bf16
  __hip_bfloat16* qrs = keys + (size_t)S_PAD * HD;              // 2048*128 bf16
  float* lsum = (float*)(qrs + (size_t)2048 * HD);              // 2048 f32

  prep_mfma<<<782, 256, 0, stream>>>(state_emb, Wk, bk, nullptr, keys,
                                     S_PAD / 16, S_TOT, 1.0f, lsum, 2048);
  prep_mfma<<<32, 256, 0, stream>>>(state_emb, Wq, bq, idcs, qrs,
                                    128, 2048, QSCALE, nullptr, 0);
  pass1<<<dim3(4, 128), 256, 0, stream>>>(keys, qrs, lsum);
  pass2<<<dim3(4, 128), 256, 0, stream>>>(keys, qrs, lsum, belief, out);
}